// Round 1
// 349.361 us; speedup vs baseline: 1.0786x; 1.0786x over previous
//
#include <hip/hip_runtime.h>
#include <hip/hip_bf16.h>
#include <hip/hip_fp16.h>
#include <math.h>

#define NFEAT 128
#define NCLASS 40

typedef __attribute__((ext_vector_type(8))) short frag_ab;   // 8 bf16 (4 VGPRs)
typedef __attribute__((ext_vector_type(4))) float frag_cd;   // 4 fp32 acc

static __device__ inline unsigned short f2bf_rne(float f) {
    union { float f; unsigned u; } v;
    v.f = f;
    unsigned r = v.u + 0x7FFFu + ((v.u >> 16) & 1u);  // round-to-nearest-even
    return (unsigned short)(r >> 16);
}
static __device__ inline float bf2f(unsigned short h) {
    union { unsigned u; float f; } v;
    v.u = ((unsigned)h) << 16;
    return v.f;
}

// ---------------- prep: conv(x->fp16) + zero(cnt) + wprep, by block range ----------------

__global__ __launch_bounds__(256) void prep_kernel(const float* __restrict__ x,
                                                   __half* __restrict__ xh, int xc4,
                                                   int* __restrict__ cnt, int n_nodes,
                                                   const float* __restrict__ W0,
                                                   const float* __restrict__ W1,
                                                   const float* __restrict__ W2,
                                                   const float* __restrict__ W3,
                                                   short* __restrict__ whi,
                                                   short* __restrict__ wlo,
                                                   int convB, int zeroB) {
    int b = blockIdx.x;
    if (b < convB) {
        int i = b * 256 + threadIdx.x;
        if (i < xc4) {
            float4 v = ((const float4*)x)[i];
            ((__half2*)xh)[i * 2 + 0] = __floats2half2_rn(v.x, v.y);
            ((__half2*)xh)[i * 2 + 1] = __floats2half2_rn(v.z, v.w);
        }
    } else if (b < convB + zeroB) {
        int i = (b - convB) * 256 + threadIdx.x;
        if (i < n_nodes) cnt[i] = 0;
    } else {
        int wb = b - convB - zeroB;        // 0..31
        int layer = wb >> 3;               // 8 blocks per layer
        const float* W = layer == 0 ? W0 : layer == 1 ? W1 : layer == 2 ? W2 : W3;
        short* h = whi + (size_t)layer * 16384;
        short* l = wlo + (size_t)layer * 16384;
        int idx = (wb & 7) * 256 + threadIdx.x;  // frag slot 0..2047
        int lane = idx & 63;
        int t = (idx >> 6) & 7;
        int s = idx >> 9;
        int quad = lane >> 4;
        int n = lane & 15;
        int kbase = s * 32 + quad * 8;
        int col = t * 16 + n;
#pragma unroll
        for (int j = 0; j < 8; ++j) {
            float f = W[(size_t)(kbase + j) * NFEAT + col];
            unsigned short hb = f2bf_rne(f);
            unsigned short lb = f2bf_rne(f - bf2f(hb));
            h[(size_t)idx * 8 + j] = (short)hb;
            l[(size_t)idx * 8 + j] = (short)lb;
        }
    }
}

// ---------------- CSR build (R6 proven) ----------------

__global__ __launch_bounds__(256) void hist_kernel(const int* __restrict__ dst,
                                                   int* __restrict__ counts, int n_edges) {
    int i = blockIdx.x * 256 + threadIdx.x;
    int n4 = n_edges >> 2;
    if (i < n4) {
        int4 d = ((const int4*)dst)[i];
        atomicAdd(&counts[d.x], 1);
        atomicAdd(&counts[d.y], 1);
        atomicAdd(&counts[d.z], 1);
        atomicAdd(&counts[d.w], 1);
    }
    if (i == 0) {
        for (int e = n4 << 2; e < n_edges; ++e) atomicAdd(&counts[dst[e]], 1);
    }
}

__global__ __launch_bounds__(256) void scan1_kernel(const int* __restrict__ cnt,
                                                    int* __restrict__ excl,
                                                    int* __restrict__ bsums, int n) {
    __shared__ int sd[256];
    int t = threadIdx.x;
    int i = blockIdx.x * 256 + t;
    int v = (i < n) ? cnt[i] : 0;
    sd[t] = v;
    __syncthreads();
#pragma unroll
    for (int off = 1; off < 256; off <<= 1) {
        int tmp = (t >= off) ? sd[t - off] : 0;
        __syncthreads();
        sd[t] += tmp;
        __syncthreads();
    }
    if (i < n) excl[i] = sd[t] - v;
    if (t == 255) bsums[blockIdx.x] = sd[255];
}

__global__ __launch_bounds__(256) void scan2_kernel(int* __restrict__ bsums, int nb) {
    __shared__ int sd[256];
    int t = threadIdx.x;
    int v = (t < nb) ? bsums[t] : 0;
    sd[t] = v;
    __syncthreads();
#pragma unroll
    for (int off = 1; off < 256; off <<= 1) {
        int tmp = (t >= off) ? sd[t - off] : 0;
        __syncthreads();
        sd[t] += tmp;
        __syncthreads();
    }
    if (t < nb) bsums[t] = sd[t] - v;
    if (t == 255) bsums[nb] = sd[255];
}

__global__ __launch_bounds__(256) void scan3_kernel(const int* __restrict__ excl,
                                                    const int* __restrict__ bsums,
                                                    int* __restrict__ row_ptr,
                                                    int* __restrict__ woff, int n, int nb) {
    int i = blockIdx.x * 256 + threadIdx.x;
    if (i < n) {
        int v = excl[i] + bsums[blockIdx.x];
        row_ptr[i] = v;
        woff[i] = v;
    }
    if (i == 0) row_ptr[n] = bsums[nb];
}

__global__ __launch_bounds__(256) void scatter_kernel(const int* __restrict__ src,
                                                      const int* __restrict__ dst,
                                                      int* __restrict__ woff,
                                                      int* __restrict__ src_sorted, int n_edges) {
    int i = blockIdx.x * 256 + threadIdx.x;
    int n4 = n_edges >> 2;
    if (i < n4) {
        int4 d = ((const int4*)dst)[i];
        int4 s = ((const int4*)src)[i];
        int p0 = atomicAdd(&woff[d.x], 1);
        int p1 = atomicAdd(&woff[d.y], 1);
        int p2 = atomicAdd(&woff[d.z], 1);
        int p3 = atomicAdd(&woff[d.w], 1);
        src_sorted[p0] = s.x;
        src_sorted[p1] = s.y;
        src_sorted[p2] = s.z;
        src_sorted[p3] = s.w;
    }
    if (i == 0) {
        for (int e = n4 << 2; e < n_edges; ++e) {
            int p = atomicAdd(&woff[dst[e]], 1);
            src_sorted[p] = src[e];
        }
    }
}

// ---------------- fused layer: gather-aggregate (fp32, LDS) + MFMA GEMM ----------------
// Phase 1: each quarter-wave (16 lanes x 16B) aggregates one node row in fp32,
//          4 passes cover the block's 64 rows; result stored to LDS [64][132] f32.
//          (pad 132: write/read bank patterns land at the 8-clk LDS minimum)
// Phase 2: split-bf16 MFMA (hi*hi + hi*lo + lo*hi) reading A-fragments from LDS.
//          fp32 -> bf16 hi+lo carries ~16 mantissa bits (better than old fp16 agg).
// Input/output ping-pong between two global fp16 buffers (no same-kernel RAW race).

__global__ __launch_bounds__(256) void gcn_fused_kernel(const __half* __restrict__ xin,
                                                        const int* __restrict__ row_ptr,
                                                        const int* __restrict__ src_sorted,
                                                        const short* __restrict__ whi,
                                                        const short* __restrict__ wlo,
                                                        const float* __restrict__ bias,
                                                        float* __restrict__ outf,
                                                        __half* __restrict__ outh, int M) {
    __shared__ float smem[64][132];
    int tid = threadIdx.x;
    int base = blockIdx.x * 64;

    // ---- phase 1: aggregate this block's 64 node rows into LDS ----
    {
        int c = tid & 15;        // 16B column group: cols [8c, 8c+8)
        int sub = tid >> 4;      // quarter-wave id 0..15
        const uint4* xp = (const uint4*)xin;  // fp16 row = 16 uint4
#pragma unroll 1
        for (int p = 0; p < 4; ++p) {
            int nl = p * 16 + sub;           // local row 0..63
            int node = base + nl;
            float a[8];
#pragma unroll
            for (int i = 0; i < 8; ++i) a[i] = 0.f;
            int jb = 0, je = 0;
            if (node < M) { jb = row_ptr[node]; je = row_ptr[node + 1]; }
            int j = jb;
            for (; j + 3 < je; j += 4) {
                int s0 = src_sorted[j];
                int s1 = src_sorted[j + 1];
                int s2 = src_sorted[j + 2];
                int s3 = src_sorted[j + 3];
                uint4 r0 = xp[s0 * 16 + c];
                uint4 r1 = xp[s1 * 16 + c];
                uint4 r2 = xp[s2 * 16 + c];
                uint4 r3 = xp[s3 * 16 + c];
#pragma unroll
                for (int q = 0; q < 4; ++q) {
                    unsigned u0 = (&r0.x)[q], u1 = (&r1.x)[q], u2 = (&r2.x)[q], u3 = (&r3.x)[q];
                    float2 f0 = __half22float2(*(__half2*)&u0);
                    float2 f1 = __half22float2(*(__half2*)&u1);
                    float2 f2 = __half22float2(*(__half2*)&u2);
                    float2 f3 = __half22float2(*(__half2*)&u3);
                    a[q * 2 + 0] += f0.x + f1.x + f2.x + f3.x;
                    a[q * 2 + 1] += f0.y + f1.y + f2.y + f3.y;
                }
            }
            for (; j < je; ++j) {
                int s0 = src_sorted[j];
                uint4 r0 = xp[s0 * 16 + c];
#pragma unroll
                for (int q = 0; q < 4; ++q) {
                    unsigned u0 = (&r0.x)[q];
                    float2 f0 = __half22float2(*(__half2*)&u0);
                    a[q * 2 + 0] += f0.x;
                    a[q * 2 + 1] += f0.y;
                }
            }
            float4* wp = (float4*)&smem[nl][c * 8];
            wp[0] = make_float4(a[0], a[1], a[2], a[3]);
            wp[1] = make_float4(a[4], a[5], a[6], a[7]);
        }
    }
    __syncthreads();

    // ---- phase 2: MFMA GEMM from LDS + bias + L2-normalize + ReLU ----
    int wave = tid >> 6;
    int lane = tid & 63;
    int quad = lane >> 4;
    int n16 = lane & 15;
    int lrow = wave * 16 + n16;  // A row within block tile

    const frag_ab* WH = (const frag_ab*)whi;
    const frag_ab* WL = (const frag_ab*)wlo;

    frag_cd acc[8];
#pragma unroll
    for (int t = 0; t < 8; ++t) acc[t] = (frag_cd){0.f, 0.f, 0.f, 0.f};

#pragma unroll
    for (int s = 0; s < 4; ++s) {
        const float* ap = &smem[lrow][s * 32 + quad * 8];
        float4 v0 = *(const float4*)(ap);
        float4 v1 = *(const float4*)(ap + 4);
        float fv[8] = {v0.x, v0.y, v0.z, v0.w, v1.x, v1.y, v1.z, v1.w};
        frag_ab ah, al;
#pragma unroll
        for (int jj = 0; jj < 8; ++jj) {
            unsigned short hb = f2bf_rne(fv[jj]);
            ah[jj] = (short)hb;
            al[jj] = (short)f2bf_rne(fv[jj] - bf2f(hb));
        }
#pragma unroll
        for (int t = 0; t < 8; ++t) {
            frag_ab bh = WH[(s * 8 + t) * 64 + lane];
            frag_ab bl = WL[(s * 8 + t) * 64 + lane];
            acc[t] = __builtin_amdgcn_mfma_f32_16x16x32_bf16(ah, bh, acc[t], 0, 0, 0);
            acc[t] = __builtin_amdgcn_mfma_f32_16x16x32_bf16(ah, bl, acc[t], 0, 0, 0);
            acc[t] = __builtin_amdgcn_mfma_f32_16x16x32_bf16(al, bh, acc[t], 0, 0, 0);
        }
    }

    // epilogue: bias -> row sum-of-squares -> normalize -> relu -> store
    float ssq[4] = {0.f, 0.f, 0.f, 0.f};
#pragma unroll
    for (int t = 0; t < 8; ++t) {
        float bv = bias[t * 16 + n16];
#pragma unroll
        for (int r = 0; r < 4; ++r) {
            acc[t][r] += bv;
            ssq[r] += acc[t][r] * acc[t][r];
        }
    }
#pragma unroll
    for (int mask = 1; mask <= 8; mask <<= 1) {
#pragma unroll
        for (int r = 0; r < 4; ++r) ssq[r] += __shfl_xor(ssq[r], mask);
    }
    float inv[4];
#pragma unroll
    for (int r = 0; r < 4; ++r) inv[r] = 1.0f / fmaxf(sqrtf(ssq[r]), 1e-12f);

    int orow0 = base + wave * 16 + quad * 4;
#pragma unroll
    for (int r = 0; r < 4; ++r) {
        int orow = orow0 + r;
        if (orow < M) {
            if (outh) {
                __half* op = outh + (size_t)orow * NFEAT + n16;
#pragma unroll
                for (int t = 0; t < 8; ++t)
                    op[t * 16] = __float2half(fmaxf(acc[t][r] * inv[r], 0.f));
            } else {
                float* op = outf + (size_t)orow * NFEAT + n16;
#pragma unroll
                for (int t = 0; t < 8; ++t)
                    op[t * 16] = fmaxf(acc[t][r] * inv[r], 0.f);
            }
        }
    }
}

// ---------------- classifier: logits = x4 @ Wl + bl; softmax (R2 proven) ----------------

__global__ __launch_bounds__(256) void classifier_kernel(const float* __restrict__ x4,
                                                         const float* __restrict__ Wl,
                                                         const float* __restrict__ bl,
                                                         float* __restrict__ logits,
                                                         float* __restrict__ probs, int n_nodes) {
    int node = blockIdx.x * 256 + threadIdx.x;
    int nc = node < n_nodes ? node : n_nodes - 1;
    const float* row = x4 + (size_t)nc * NFEAT;

    float acc[NCLASS];
#pragma unroll
    for (int c = 0; c < NCLASS; ++c) acc[c] = bl[c];

    for (int k = 0; k < NFEAT; k += 4) {
        float4 a = *(const float4*)(row + k);
#pragma unroll
        for (int kk = 0; kk < 4; ++kk) {
            float av = (&a.x)[kk];
            const float* Wr = Wl + (k + kk) * NCLASS;
#pragma unroll
            for (int c = 0; c < NCLASS; ++c) acc[c] += av * Wr[c];
        }
    }

    float m = acc[0];
#pragma unroll
    for (int c = 1; c < NCLASS; ++c) m = fmaxf(m, acc[c]);
    float ex[NCLASS];
    float sum = 0.f;
#pragma unroll
    for (int c = 0; c < NCLASS; ++c) {
        ex[c] = __expf(acc[c] - m);
        sum += ex[c];
    }
    float is = 1.0f / sum;

    if (node < n_nodes) {
        float4* lo = (float4*)(logits + (size_t)node * NCLASS);
        float4* po = (float4*)(probs + (size_t)node * NCLASS);
#pragma unroll
        for (int c = 0; c < NCLASS; c += 4) {
            float4 lv, pv;
            lv.x = acc[c + 0]; lv.y = acc[c + 1]; lv.z = acc[c + 2]; lv.w = acc[c + 3];
            pv.x = ex[c + 0] * is; pv.y = ex[c + 1] * is; pv.z = ex[c + 2] * is; pv.w = ex[c + 3] * is;
            lo[c >> 2] = lv;
            po[c >> 2] = pv;
        }
    }
}

// ---------------- launch ----------------

extern "C" void kernel_launch(void* const* d_in, const int* in_sizes, int n_in,
                              void* d_out, int out_size, void* d_ws, size_t ws_size,
                              hipStream_t stream) {
    const float* x  = (const float*)d_in[0];
    const int*   ei = (const int*)d_in[1];
    const float* W1 = (const float*)d_in[2];
    const float* b1 = (const float*)d_in[3];
    const float* W2 = (const float*)d_in[4];
    const float* b2 = (const float*)d_in[5];
    const float* W3 = (const float*)d_in[6];
    const float* b3 = (const float*)d_in[7];
    const float* W4 = (const float*)d_in[8];
    const float* b4 = (const float*)d_in[9];
    const float* Wl = (const float*)d_in[10];
    const float* bl = (const float*)d_in[11];

    const int n_nodes = in_sizes[0] / NFEAT;  // 50000
    const int n_edges = in_sizes[1] / 2;      // 640000
    const int* src = ei;
    const int* dst = ei + n_edges;

    float* out    = (float*)d_out;
    float* logits = out;
    float* probs  = out + (size_t)n_nodes * NCLASS;
    float* x4     = out + 2 * (size_t)n_nodes * NCLASS;  // final fp32 features

    char* ws = (char*)d_ws;
    size_t off = 0;
    auto wsalloc = [&](size_t bytes) -> void* {
        void* p = ws + off;
        off += (bytes + 255) & ~(size_t)255;
        return p;
    };
    __half* xh         = (__half*)wsalloc((size_t)n_nodes * NFEAT * sizeof(__half));
    __half* xh2        = (__half*)wsalloc((size_t)n_nodes * NFEAT * sizeof(__half));
    int*    row_ptr    = (int*)wsalloc(((size_t)n_nodes + 1) * sizeof(int));
    int*    woff       = (int*)wsalloc((size_t)n_nodes * sizeof(int));
    int*    cnt        = (int*)wsalloc((size_t)n_nodes * sizeof(int));
    int*    src_sorted = (int*)wsalloc((size_t)n_edges * sizeof(int));
    int     nbt        = (n_nodes + 255) / 256;
    int*    bsums      = (int*)wsalloc(((size_t)nbt + 1) * sizeof(int));
    short*  whi        = (short*)wsalloc((size_t)4 * 16384 * sizeof(short));
    short*  wlo        = (short*)wsalloc((size_t)4 * 16384 * sizeof(short));

    // dispatch 1: prep (conv + zero cnt + wprep)
    int xc4   = (n_nodes * NFEAT) / 4;
    int convB = (xc4 + 255) / 256;
    int zeroB = (n_nodes + 255) / 256;
    prep_kernel<<<convB + zeroB + 32, 256, 0, stream>>>(x, xh, xc4, cnt, n_nodes,
                                                        W1, W2, W3, W4, whi, wlo,
                                                        convB, zeroB);

    // CSR build (dst-bucketed)
    int e4b = ((n_edges >> 2) + 255) / 256;
    hist_kernel<<<e4b, 256, 0, stream>>>(dst, cnt, n_edges);
    scan1_kernel<<<nbt, 256, 0, stream>>>(cnt, row_ptr /*excl temp*/, bsums, n_nodes);
    scan2_kernel<<<1, 256, 0, stream>>>(bsums, nbt);
    scan3_kernel<<<nbt, 256, 0, stream>>>(row_ptr, bsums, row_ptr, woff, n_nodes, nbt);
    scatter_kernel<<<e4b, 256, 0, stream>>>(src, dst, woff, src_sorted, n_edges);

    int gb = (n_nodes + 63) / 64;
    int cb = (n_nodes + 255) / 256;

    // fused agg+GEMM layers, ping-pong xh <-> xh2
    gcn_fused_kernel<<<gb, 256, 0, stream>>>(xh,  row_ptr, src_sorted, whi + 0 * 16384, wlo + 0 * 16384, b1, nullptr, xh2, n_nodes);
    gcn_fused_kernel<<<gb, 256, 0, stream>>>(xh2, row_ptr, src_sorted, whi + 1 * 16384, wlo + 1 * 16384, b2, nullptr, xh,  n_nodes);
    gcn_fused_kernel<<<gb, 256, 0, stream>>>(xh,  row_ptr, src_sorted, whi + 2 * 16384, wlo + 2 * 16384, b3, nullptr, xh2, n_nodes);
    gcn_fused_kernel<<<gb, 256, 0, stream>>>(xh2, row_ptr, src_sorted, whi + 3 * 16384, wlo + 3 * 16384, b4, x4, nullptr, n_nodes);

    // classifier + softmax
    classifier_kernel<<<cb, 256, 0, stream>>>(x4, Wl, bl, logits, probs, n_nodes);
}

// Round 2
// 347.781 us; speedup vs baseline: 1.0835x; 1.0045x over previous
//
#include <hip/hip_runtime.h>
#include <hip/hip_bf16.h>
#include <hip/hip_fp16.h>
#include <math.h>

#define NFEAT 128
#define NCLASS 40

typedef __attribute__((ext_vector_type(8))) short frag_ab;   // 8 bf16 (4 VGPRs)
typedef __attribute__((ext_vector_type(4))) float frag_cd;   // 4 fp32 acc

static __device__ inline unsigned short f2bf_rne(float f) {
    union { float f; unsigned u; } v;
    v.f = f;
    unsigned r = v.u + 0x7FFFu + ((v.u >> 16) & 1u);  // round-to-nearest-even
    return (unsigned short)(r >> 16);
}
static __device__ inline float bf2f(unsigned short h) {
    union { unsigned u; float f; } v;
    v.u = ((unsigned)h) << 16;
    return v.f;
}

// ---------------- prep: conv(x->fp16) + wprep + hist, by block range ----------------
// cnt is pre-zeroed by hipMemsetAsync, so the dst-histogram can run inside prep
// (it only reads edge dst; independent of conv/wprep).

__global__ __launch_bounds__(256) void prep_kernel(const float* __restrict__ x,
                                                   __half* __restrict__ xh, int xc4,
                                                   const float* __restrict__ W0,
                                                   const float* __restrict__ W1,
                                                   const float* __restrict__ W2,
                                                   const float* __restrict__ W3,
                                                   short* __restrict__ whi,
                                                   short* __restrict__ wlo,
                                                   const int* __restrict__ dst,
                                                   int* __restrict__ cnt, int n_edges,
                                                   int convB) {
    int b = blockIdx.x;
    if (b < convB) {
        int i = b * 256 + threadIdx.x;
        if (i < xc4) {
            float4 v = ((const float4*)x)[i];
            ((__half2*)xh)[i * 2 + 0] = __floats2half2_rn(v.x, v.y);
            ((__half2*)xh)[i * 2 + 1] = __floats2half2_rn(v.z, v.w);
        }
    } else if (b < convB + 32) {
        int wb = b - convB;                // 0..31
        int layer = wb >> 3;               // 8 blocks per layer
        const float* W = layer == 0 ? W0 : layer == 1 ? W1 : layer == 2 ? W2 : W3;
        short* h = whi + (size_t)layer * 16384;
        short* l = wlo + (size_t)layer * 16384;
        int idx = (wb & 7) * 256 + threadIdx.x;  // frag slot 0..2047
        int lane = idx & 63;
        int t = (idx >> 6) & 7;
        int s = idx >> 9;
        int quad = lane >> 4;
        int n = lane & 15;
        int kbase = s * 32 + quad * 8;
        int col = t * 16 + n;
#pragma unroll
        for (int j = 0; j < 8; ++j) {
            float f = W[(size_t)(kbase + j) * NFEAT + col];
            unsigned short hb = f2bf_rne(f);
            unsigned short lb = f2bf_rne(f - bf2f(hb));
            h[(size_t)idx * 8 + j] = (short)hb;
            l[(size_t)idx * 8 + j] = (short)lb;
        }
    } else {
        int hb = b - convB - 32;
        int i = hb * 256 + threadIdx.x;
        int n4 = n_edges >> 2;
        if (i < n4) {
            int4 d = ((const int4*)dst)[i];
            atomicAdd(&cnt[d.x], 1);
            atomicAdd(&cnt[d.y], 1);
            atomicAdd(&cnt[d.z], 1);
            atomicAdd(&cnt[d.w], 1);
        }
        if (hb == 0 && threadIdx.x == 0) {
            for (int e = n4 << 2; e < n_edges; ++e) atomicAdd(&cnt[dst[e]], 1);
        }
    }
}

// ---------------- CSR build ----------------

__global__ __launch_bounds__(256) void scan1_kernel(const int* __restrict__ cnt,
                                                    int* __restrict__ excl,
                                                    int* __restrict__ bsums, int n) {
    __shared__ int sd[256];
    int t = threadIdx.x;
    int i = blockIdx.x * 256 + t;
    int v = (i < n) ? cnt[i] : 0;
    sd[t] = v;
    __syncthreads();
#pragma unroll
    for (int off = 1; off < 256; off <<= 1) {
        int tmp = (t >= off) ? sd[t - off] : 0;
        __syncthreads();
        sd[t] += tmp;
        __syncthreads();
    }
    if (i < n) excl[i] = sd[t] - v;
    if (t == 255) bsums[blockIdx.x] = sd[255];
}

// scan3 now also performs scan2's job: every block re-scans the (<=256) block
// sums in LDS to derive its own offset and the grand total.
__global__ __launch_bounds__(256) void scan3_kernel(const int* __restrict__ excl,
                                                    const int* __restrict__ bsums,
                                                    int* __restrict__ row_ptr,
                                                    int* __restrict__ woff, int n, int nb) {
    __shared__ int sd[256];
    __shared__ int off_s, tot_s;
    int t = threadIdx.x;
    int v = (t < nb) ? bsums[t] : 0;
    sd[t] = v;
    __syncthreads();
#pragma unroll
    for (int off = 1; off < 256; off <<= 1) {
        int tmp = (t >= off) ? sd[t - off] : 0;
        __syncthreads();
        sd[t] += tmp;
        __syncthreads();
    }
    if (t == 0) {
        off_s = (blockIdx.x > 0) ? sd[blockIdx.x - 1] : 0;
        tot_s = sd[255];
    }
    __syncthreads();
    int i = blockIdx.x * 256 + t;
    if (i < n) {
        int val = excl[i] + off_s;
        row_ptr[i] = val;
        woff[i] = val;
    }
    if (i == 0) row_ptr[n] = tot_s;
}

__global__ __launch_bounds__(256) void scatter_kernel(const int* __restrict__ src,
                                                      const int* __restrict__ dst,
                                                      int* __restrict__ woff,
                                                      int* __restrict__ src_sorted, int n_edges) {
    int i = blockIdx.x * 256 + threadIdx.x;
    int n4 = n_edges >> 2;
    if (i < n4) {
        int4 d = ((const int4*)dst)[i];
        int4 s = ((const int4*)src)[i];
        int p0 = atomicAdd(&woff[d.x], 1);
        int p1 = atomicAdd(&woff[d.y], 1);
        int p2 = atomicAdd(&woff[d.z], 1);
        int p3 = atomicAdd(&woff[d.w], 1);
        src_sorted[p0] = s.x;
        src_sorted[p1] = s.y;
        src_sorted[p2] = s.z;
        src_sorted[p3] = s.w;
    }
    if (i == 0) {
        for (int e = n4 << 2; e < n_edges; ++e) {
            int p = atomicAdd(&woff[dst[e]], 1);
            src_sorted[p] = src[e];
        }
    }
}

// ---------------- fused layer: gather-aggregate (fp32, LDS) + MFMA GEMM ----------------
// Phase 1: quarter-waves (16 lanes x 16B) claim node rows via an LDS work-steal
//          counter (balances Poisson degree variance; static 4-pass assignment
//          made block time ~1.3x the mean), aggregate in fp32, store to LDS.
// Phase 2: split-bf16 MFMA (hi*hi + hi*lo + lo*hi) reading A-fragments from LDS.
// Input/output ping-pong between two global fp16 buffers.

__global__ __launch_bounds__(256) void gcn_fused_kernel(const __half* __restrict__ xin,
                                                        const int* __restrict__ row_ptr,
                                                        const int* __restrict__ src_sorted,
                                                        const short* __restrict__ whi,
                                                        const short* __restrict__ wlo,
                                                        const float* __restrict__ bias,
                                                        float* __restrict__ outf,
                                                        __half* __restrict__ outh, int M) {
    __shared__ float smem[64][132];
    __shared__ int ctr;
    int tid = threadIdx.x;
    int base = blockIdx.x * 64;
    if (tid == 0) ctr = 0;
    __syncthreads();

    // ---- phase 1: aggregate this block's 64 node rows into LDS (work-steal) ----
    {
        int c = tid & 15;        // 16B column group: cols [8c, 8c+8)
        int lane = tid & 63;
        const uint4* xp = (const uint4*)xin;  // fp16 row = 16 uint4
        for (;;) {
            int nl = 0;
            if ((lane & 15) == 0) nl = atomicAdd(&ctr, 1);
            nl = __shfl(nl, lane & 48);      // broadcast from quarter-wave leader
            if (nl >= 64) break;
            int node = base + nl;
            float a[8];
#pragma unroll
            for (int i = 0; i < 8; ++i) a[i] = 0.f;
            int jb = 0, je = 0;
            if (node < M) { jb = row_ptr[node]; je = row_ptr[node + 1]; }
            int j = jb;
            for (; j + 3 < je; j += 4) {
                int s0 = src_sorted[j];
                int s1 = src_sorted[j + 1];
                int s2 = src_sorted[j + 2];
                int s3 = src_sorted[j + 3];
                uint4 r0 = xp[s0 * 16 + c];
                uint4 r1 = xp[s1 * 16 + c];
                uint4 r2 = xp[s2 * 16 + c];
                uint4 r3 = xp[s3 * 16 + c];
#pragma unroll
                for (int q = 0; q < 4; ++q) {
                    unsigned u0 = (&r0.x)[q], u1 = (&r1.x)[q], u2 = (&r2.x)[q], u3 = (&r3.x)[q];
                    float2 f0 = __half22float2(*(__half2*)&u0);
                    float2 f1 = __half22float2(*(__half2*)&u1);
                    float2 f2 = __half22float2(*(__half2*)&u2);
                    float2 f3 = __half22float2(*(__half2*)&u3);
                    a[q * 2 + 0] += f0.x + f1.x + f2.x + f3.x;
                    a[q * 2 + 1] += f0.y + f1.y + f2.y + f3.y;
                }
            }
            for (; j < je; ++j) {
                int s0 = src_sorted[j];
                uint4 r0 = xp[s0 * 16 + c];
#pragma unroll
                for (int q = 0; q < 4; ++q) {
                    unsigned u0 = (&r0.x)[q];
                    float2 f0 = __half22float2(*(__half2*)&u0);
                    a[q * 2 + 0] += f0.x;
                    a[q * 2 + 1] += f0.y;
                }
            }
            float4* wp = (float4*)&smem[nl][c * 8];
            wp[0] = make_float4(a[0], a[1], a[2], a[3]);
            wp[1] = make_float4(a[4], a[5], a[6], a[7]);
        }
    }
    __syncthreads();

    // ---- phase 2: MFMA GEMM from LDS + bias + L2-normalize + ReLU ----
    int wave = tid >> 6;
    int lane = tid & 63;
    int quad = lane >> 4;
    int n16 = lane & 15;
    int lrow = wave * 16 + n16;  // A row within block tile

    const frag_ab* WH = (const frag_ab*)whi;
    const frag_ab* WL = (const frag_ab*)wlo;

    frag_cd acc[8];
#pragma unroll
    for (int t = 0; t < 8; ++t) acc[t] = (frag_cd){0.f, 0.f, 0.f, 0.f};

#pragma unroll
    for (int s = 0; s < 4; ++s) {
        const float* ap = &smem[lrow][s * 32 + quad * 8];
        float4 v0 = *(const float4*)(ap);
        float4 v1 = *(const float4*)(ap + 4);
        float fv[8] = {v0.x, v0.y, v0.z, v0.w, v1.x, v1.y, v1.z, v1.w};
        frag_ab ah, al;
#pragma unroll
        for (int jj = 0; jj < 8; ++jj) {
            unsigned short hb = f2bf_rne(fv[jj]);
            ah[jj] = (short)hb;
            al[jj] = (short)f2bf_rne(fv[jj] - bf2f(hb));
        }
#pragma unroll
        for (int t = 0; t < 8; ++t) {
            frag_ab bh = WH[(s * 8 + t) * 64 + lane];
            frag_ab bl = WL[(s * 8 + t) * 64 + lane];
            acc[t] = __builtin_amdgcn_mfma_f32_16x16x32_bf16(ah, bh, acc[t], 0, 0, 0);
            acc[t] = __builtin_amdgcn_mfma_f32_16x16x32_bf16(ah, bl, acc[t], 0, 0, 0);
            acc[t] = __builtin_amdgcn_mfma_f32_16x16x32_bf16(al, bh, acc[t], 0, 0, 0);
        }
    }

    // epilogue: bias -> row sum-of-squares -> normalize -> relu -> store
    float ssq[4] = {0.f, 0.f, 0.f, 0.f};
#pragma unroll
    for (int t = 0; t < 8; ++t) {
        float bv = bias[t * 16 + n16];
#pragma unroll
        for (int r = 0; r < 4; ++r) {
            acc[t][r] += bv;
            ssq[r] += acc[t][r] * acc[t][r];
        }
    }
#pragma unroll
    for (int mask = 1; mask <= 8; mask <<= 1) {
#pragma unroll
        for (int r = 0; r < 4; ++r) ssq[r] += __shfl_xor(ssq[r], mask);
    }
    float inv[4];
#pragma unroll
    for (int r = 0; r < 4; ++r) inv[r] = 1.0f / fmaxf(sqrtf(ssq[r]), 1e-12f);

    int orow0 = base + wave * 16 + quad * 4;
#pragma unroll
    for (int r = 0; r < 4; ++r) {
        int orow = orow0 + r;
        if (orow < M) {
            if (outh) {
                __half* op = outh + (size_t)orow * NFEAT + n16;
#pragma unroll
                for (int t = 0; t < 8; ++t)
                    op[t * 16] = __float2half(fmaxf(acc[t][r] * inv[r], 0.f));
            } else {
                float* op = outf + (size_t)orow * NFEAT + n16;
#pragma unroll
                for (int t = 0; t < 8; ++t)
                    op[t * 16] = fmaxf(acc[t][r] * inv[r], 0.f);
            }
        }
    }
}

// ---------------- classifier: logits = x4 @ Wl + bl; softmax ----------------

__global__ __launch_bounds__(256) void classifier_kernel(const float* __restrict__ x4,
                                                         const float* __restrict__ Wl,
                                                         const float* __restrict__ bl,
                                                         float* __restrict__ logits,
                                                         float* __restrict__ probs, int n_nodes) {
    int node = blockIdx.x * 256 + threadIdx.x;
    int nc = node < n_nodes ? node : n_nodes - 1;
    const float* row = x4 + (size_t)nc * NFEAT;

    float acc[NCLASS];
#pragma unroll
    for (int c = 0; c < NCLASS; ++c) acc[c] = bl[c];

    for (int k = 0; k < NFEAT; k += 4) {
        float4 a = *(const float4*)(row + k);
#pragma unroll
        for (int kk = 0; kk < 4; ++kk) {
            float av = (&a.x)[kk];
            const float* Wr = Wl + (k + kk) * NCLASS;
#pragma unroll
            for (int c = 0; c < NCLASS; ++c) acc[c] += av * Wr[c];
        }
    }

    float m = acc[0];
#pragma unroll
    for (int c = 1; c < NCLASS; ++c) m = fmaxf(m, acc[c]);
    float ex[NCLASS];
    float sum = 0.f;
#pragma unroll
    for (int c = 0; c < NCLASS; ++c) {
        ex[c] = __expf(acc[c] - m);
        sum += ex[c];
    }
    float is = 1.0f / sum;

    if (node < n_nodes) {
        float4* lo = (float4*)(logits + (size_t)node * NCLASS);
        float4* po = (float4*)(probs + (size_t)node * NCLASS);
#pragma unroll
        for (int c = 0; c < NCLASS; c += 4) {
            float4 lv, pv;
            lv.x = acc[c + 0]; lv.y = acc[c + 1]; lv.z = acc[c + 2]; lv.w = acc[c + 3];
            pv.x = ex[c + 0] * is; pv.y = ex[c + 1] * is; pv.z = ex[c + 2] * is; pv.w = ex[c + 3] * is;
            lo[c >> 2] = lv;
            po[c >> 2] = pv;
        }
    }
}

// ---------------- launch ----------------

extern "C" void kernel_launch(void* const* d_in, const int* in_sizes, int n_in,
                              void* d_out, int out_size, void* d_ws, size_t ws_size,
                              hipStream_t stream) {
    const float* x  = (const float*)d_in[0];
    const int*   ei = (const int*)d_in[1];
    const float* W1 = (const float*)d_in[2];
    const float* b1 = (const float*)d_in[3];
    const float* W2 = (const float*)d_in[4];
    const float* b2 = (const float*)d_in[5];
    const float* W3 = (const float*)d_in[6];
    const float* b3 = (const float*)d_in[7];
    const float* W4 = (const float*)d_in[8];
    const float* b4 = (const float*)d_in[9];
    const float* Wl = (const float*)d_in[10];
    const float* bl = (const float*)d_in[11];

    const int n_nodes = in_sizes[0] / NFEAT;  // 50000
    const int n_edges = in_sizes[1] / 2;      // 640000
    const int* src = ei;
    const int* dst = ei + n_edges;

    float* out    = (float*)d_out;
    float* logits = out;
    float* probs  = out + (size_t)n_nodes * NCLASS;
    float* x4     = out + 2 * (size_t)n_nodes * NCLASS;  // final fp32 features

    char* ws = (char*)d_ws;
    size_t off = 0;
    auto wsalloc = [&](size_t bytes) -> void* {
        void* p = ws + off;
        off += (bytes + 255) & ~(size_t)255;
        return p;
    };
    __half* xh         = (__half*)wsalloc((size_t)n_nodes * NFEAT * sizeof(__half));
    __half* xh2        = (__half*)wsalloc((size_t)n_nodes * NFEAT * sizeof(__half));
    int*    row_ptr    = (int*)wsalloc(((size_t)n_nodes + 1) * sizeof(int));
    int*    woff       = (int*)wsalloc((size_t)n_nodes * sizeof(int));
    int*    cnt        = (int*)wsalloc((size_t)n_nodes * sizeof(int));
    int*    src_sorted = (int*)wsalloc((size_t)n_edges * sizeof(int));
    int     nbt        = (n_nodes + 255) / 256;
    int*    bsums      = (int*)wsalloc(((size_t)nbt + 1) * sizeof(int));
    short*  whi        = (short*)wsalloc((size_t)4 * 16384 * sizeof(short));
    short*  wlo        = (short*)wsalloc((size_t)4 * 16384 * sizeof(short));

    // zero the histogram counters (graph-capturable async fill)
    hipMemsetAsync(cnt, 0, (size_t)n_nodes * sizeof(int), stream);

    // dispatch: prep (conv + wprep + hist)
    int xc4   = (n_nodes * NFEAT) / 4;
    int convB = (xc4 + 255) / 256;
    int e4b   = ((n_edges >> 2) + 255) / 256;
    prep_kernel<<<convB + 32 + e4b, 256, 0, stream>>>(x, xh, xc4,
                                                      W1, W2, W3, W4, whi, wlo,
                                                      dst, cnt, n_edges, convB);

    // CSR build (dst-bucketed); scan2 folded into scan3
    scan1_kernel<<<nbt, 256, 0, stream>>>(cnt, row_ptr /*excl temp*/, bsums, n_nodes);
    scan3_kernel<<<nbt, 256, 0, stream>>>(row_ptr, bsums, row_ptr, woff, n_nodes, nbt);
    scatter_kernel<<<e4b, 256, 0, stream>>>(src, dst, woff, src_sorted, n_edges);

    int gb = (n_nodes + 63) / 64;
    int cb = (n_nodes + 255) / 256;

    // fused agg+GEMM layers, ping-pong xh <-> xh2
    gcn_fused_kernel<<<gb, 256, 0, stream>>>(xh,  row_ptr, src_sorted, whi + 0 * 16384, wlo + 0 * 16384, b1, nullptr, xh2, n_nodes);
    gcn_fused_kernel<<<gb, 256, 0, stream>>>(xh2, row_ptr, src_sorted, whi + 1 * 16384, wlo + 1 * 16384, b2, nullptr, xh,  n_nodes);
    gcn_fused_kernel<<<gb, 256, 0, stream>>>(xh,  row_ptr, src_sorted, whi + 2 * 16384, wlo + 2 * 16384, b3, nullptr, xh2, n_nodes);
    gcn_fused_kernel<<<gb, 256, 0, stream>>>(xh2, row_ptr, src_sorted, whi + 3 * 16384, wlo + 3 * 16384, b4, x4, nullptr, n_nodes);

    // classifier + softmax
    classifier_kernel<<<cb, 256, 0, stream>>>(x4, Wl, bl, logits, probs, n_nodes);
}